// Round 3
// baseline (286.020 us; speedup 1.0000x reference)
//
#include <hip/hip_runtime.h>
#include <hip/hip_bf16.h>
#include <stdint.h>
#include <stddef.h>

typedef __bf16 bf16;
typedef float f32x4 __attribute__((ext_vector_type(4)));
typedef bf16 bf16x8 __attribute__((ext_vector_type(8)));
typedef bf16 bf16x4 __attribute__((ext_vector_type(4)));

#define MROWS 8192
#define NOUT 256
#define BM 32
#define BK 128
#define NTHREADS 512

#define LDS_A_BYTES (BM * BK * 2)  // 8 KiB bf16 A tile; x2 double-buffer = 16 KiB total

#define SCHED0 __builtin_amdgcn_sched_barrier(0)
#define SBAR __builtin_amdgcn_s_barrier()

// C = A(fp32, lda) @ B^T(bf16 [NOUT][K]) with fused epilogue.
// B fragments are loaded straight from global (L2/L3-resident) into registers,
// prefetched one K-step ahead; only A goes through LDS (cvt + cross-wave share).
// OUTT: write bf16 transposed Ct[n][m] (opt. scaled by filt[m]); else fp32 C[m][n].
template <bool SCALE, bool OUTT>
__global__ __launch_bounds__(NTHREADS, 1) void gemm_fused(
    const float* __restrict__ A, const bf16* __restrict__ Bt,
    const float* __restrict__ filt, void* __restrict__ outp,
    const int K, const int lda) {
  __shared__ char lds[2][LDS_A_BYTES];
  const int t = threadIdx.x;
  const int w = t >> 6;
  const int l = t & 63;
  const int m0 = blockIdx.x * BM;
  const int NT = K / BK;

  // ---- A staging map: thread -> (row, 8-float chunk); cvt bf16, swizzled ds_write
  const int ar = t >> 4;
  const int acb = t & 15;
  const float* gA = A + (size_t)(m0 + ar) * (size_t)lda + acb * 8;
  const int a_lds_off = (ar * (BK * 2) + acb * 16) ^ ((ar & 7) << 4);

  // ---- A fragment read offsets (XOR-swizzled, [32][256B] tile)
  int aoff[2][4];
#pragma unroll
  for (int af = 0; af < 2; ++af)
#pragma unroll
    for (int ak = 0; ak < 4; ++ak) {
      const int r = af * 16 + (l & 15);
      const int kb = ak * 64 + (l >> 4) * 16;
      aoff[af][ak] = (r * (BK * 2) + kb) ^ ((r & 7) << 4);
    }

  // ---- B fragment global base pointers (per-wave, no redundancy):
  //      frag(bfi,ak) at step ts = pB[bfi] + ts*BK + ak*32  (elements)
  const bf16* pB[2];
#pragma unroll
  for (int bfi = 0; bfi < 2; ++bfi)
    pB[bfi] = Bt + (size_t)(w * 32 + bfi * 16 + (l & 15)) * (size_t)K + (l >> 4) * 8;

  f32x4 acc[2][2] = {};

  // ================= prologue =================
  f32x4 aS0a = __builtin_nontemporal_load((const f32x4*)gA);
  f32x4 aS0b = __builtin_nontemporal_load((const f32x4*)gA + 1);
  f32x4 aS1a = __builtin_nontemporal_load((const f32x4*)(gA + BK));
  f32x4 aS1b = __builtin_nontemporal_load((const f32x4*)(gA + BK) + 1);
  bf16x8 Bc[2][4], Bn[2][4];
#pragma unroll
  for (int bfi = 0; bfi < 2; ++bfi)
#pragma unroll
    for (int ak = 0; ak < 4; ++ak)
      Bc[bfi][ak] = *(const bf16x8*)(pB[bfi] + ak * 32);
  {
    bf16x8 pk;
#pragma unroll
    for (int j = 0; j < 4; ++j) {
      pk[j] = (bf16)aS0a[j];
      pk[j + 4] = (bf16)aS0b[j];
    }
    *(bf16x8*)(lds[0] + a_lds_off) = pk;
  }
  asm volatile("s_waitcnt lgkmcnt(0)" ::: "memory");
  SBAR;
  SCHED0;

  // ================= main loop (unrolled x2 for static reg-set indexing) =================
  // BODY(TS): read A-frags from lds[P]; issue B(TS+1)->BNXT, A(TS+2)->AL;
  // MFMA(afr x BCUR); cvt AW(=A(TS+1)) -> lds[P^1]; lgkm drain; barrier.
  // B/A prefetch loads stay in flight across the barrier (register loads,
  // compiler inserts exact counted vmcnt at first use).
#define BODY(TS, P, BCUR, BNXT, AW0, AW1, AL0, AL1)                           \
  {                                                                           \
    const char* bb = lds[P];                                                  \
    bf16x8 afr[2][4];                                                         \
    _Pragma("unroll") for (int af = 0; af < 2; ++af)                          \
        _Pragma("unroll") for (int ak = 0; ak < 4; ++ak)                      \
            afr[af][ak] = *(const bf16x8*)(bb + aoff[af][ak]);                \
    SCHED0;                                                                   \
    const int kb1 = (((TS) + 1) < NT ? ((TS) + 1) : 0) * BK;                  \
    _Pragma("unroll") for (int bfi = 0; bfi < 2; ++bfi)                       \
        _Pragma("unroll") for (int ak = 0; ak < 4; ++ak)                      \
            BNXT[bfi][ak] = *(const bf16x8*)(pB[bfi] + kb1 + ak * 32);        \
    SCHED0;                                                                   \
    const int ka2 = (((TS) + 2) < NT ? ((TS) + 2) : 0) * BK;                  \
    AL0 = __builtin_nontemporal_load((const f32x4*)(gA + ka2));               \
    AL1 = __builtin_nontemporal_load((const f32x4*)(gA + ka2) + 1);           \
    SCHED0;                                                                   \
    asm volatile("s_waitcnt lgkmcnt(0)" ::: "memory");                        \
    SCHED0;                                                                   \
    __builtin_amdgcn_s_setprio(1);                                            \
    _Pragma("unroll") for (int ak = 0; ak < 4; ++ak)                          \
        _Pragma("unroll") for (int af = 0; af < 2; ++af)                      \
            _Pragma("unroll") for (int bfi = 0; bfi < 2; ++bfi)               \
                acc[af][bfi] = __builtin_amdgcn_mfma_f32_16x16x32_bf16(       \
                    afr[af][ak], BCUR[bfi][ak], acc[af][bfi], 0, 0, 0);       \
    __builtin_amdgcn_s_setprio(0);                                            \
    SCHED0;                                                                   \
    {                                                                         \
      bf16x8 pk;                                                              \
      _Pragma("unroll") for (int j = 0; j < 4; ++j) {                         \
        pk[j] = (bf16)AW0[j];                                                 \
        pk[j + 4] = (bf16)AW1[j];                                             \
      }                                                                       \
      *(bf16x8*)(lds[P ^ 1] + a_lds_off) = pk;                                \
    }                                                                         \
    asm volatile("s_waitcnt lgkmcnt(0)" ::: "memory");                        \
    SBAR;                                                                     \
    SCHED0;                                                                   \
  }

  for (int ts = 0; ts < NT; ts += 2) {
    BODY(ts, 0, Bc, Bn, aS1a, aS1b, aS0a, aS0b);
    BODY(ts + 1, 1, Bn, Bc, aS0a, aS0b, aS1a, aS1b);
  }
#undef BODY

  // ---- epilogue (C/D: col = lane&15, row = (lane>>4)*4 + reg)
#pragma unroll
  for (int af = 0; af < 2; ++af)
#pragma unroll
    for (int bfi = 0; bfi < 2; ++bfi) {
      const int mb = m0 + af * 16 + (l >> 4) * 4;
      const int n = w * 32 + bfi * 16 + (l & 15);
      f32x4 v = acc[af][bfi];
      if (SCALE) {
#pragma unroll
        for (int j = 0; j < 4; ++j) v[j] *= filt[mb + j];
      }
      if (OUTT) {
        bf16x4 pv;
#pragma unroll
        for (int j = 0; j < 4; ++j) pv[j] = (bf16)v[j];
        *(bf16x4*)((bf16*)outp + (size_t)n * MROWS + mb) = pv;
      } else {
        float* po = (float*)outp + (size_t)mb * NOUT + n;
#pragma unroll
        for (int j = 0; j < 4; ++j) po[(size_t)j * NOUT] = v[j];
      }
    }
}

// W [256][256] fp32 -> Wt [n][k] bf16 (transpose + convert)
__global__ void prep_wt(const float* __restrict__ W, bf16* __restrict__ Wt) {
  const int k = blockIdx.x;
  const int n = threadIdx.x;
  Wt[(size_t)n * 256 + k] = (bf16)W[(size_t)k * 256 + n];
}

extern "C" void kernel_launch(void* const* d_in, const int* in_sizes, int n_in,
                              void* d_out, int out_size, void* d_ws, size_t ws_size,
                              hipStream_t stream) {
  const float* features = (const float*)d_in[0];
  const float* wavelets = (const float*)d_in[1];
  const float* wavelets_inv = (const float*)d_in[2];
  const float* W = (const float*)d_in[3];
  const float* filt = (const float*)d_in[4];
  float* out = (float*)d_out;

  char* ws = (char*)d_ws;
  bf16* Wt = (bf16*)ws;                       // 128 KiB
  bf16* Tt = (bf16*)(ws + 131072);            // 4 MiB: (features@W)^T
  bf16* Ft = (bf16*)(ws + 131072 + 4194304);  // 4 MiB: (filt*spectral)^T

  prep_wt<<<256, 256, 0, stream>>>(W, Wt);
  gemm_fused<false, true><<<256, NTHREADS, 0, stream>>>(features, Wt, nullptr, Tt, 256, 256);
  gemm_fused<true, true><<<256, NTHREADS, 0, stream>>>(wavelets_inv, Tt, filt, Ft, 8192, 8192);
  gemm_fused<false, false><<<256, NTHREADS, 0, stream>>>(wavelets, Ft, nullptr, out, 8192, 8192);
}

// Round 4
// 192.100 us; speedup vs baseline: 1.4889x; 1.4889x over previous
//
#include <hip/hip_runtime.h>
#include <hip/hip_bf16.h>
#include <stdint.h>
#include <stddef.h>

typedef __bf16 bf16;
typedef float f32x4 __attribute__((ext_vector_type(4)));
typedef bf16 bf16x8 __attribute__((ext_vector_type(8)));
typedef bf16 bf16x4 __attribute__((ext_vector_type(4)));

#define MROWS 8192
#define NOUT 256
#define BM 32
#define BK 128
#define NTHREADS 512

#define LDS_A_BYTES (BM * BK * 2)  // 8 KiB bf16 A tile; x2 double-buffer

#define SCHED0 __builtin_amdgcn_sched_barrier(0)
#define SBAR __builtin_amdgcn_s_barrier()

// ---------------------------------------------------------------------------
// B is kept in "fragment-permuted" layout Bp: for K-step ts, wave w, fragment
// (bfi,ak), lane l, the 16-byte lane chunk lives at byte offset
//   (ts*64 + w*8 + bfi*4 + ak)*1024 + l*16
// holding B[n][k0..k0+7] with n = w*32+bfi*16+(l&15), k0 = ts*128+ak*32+(l>>4)*8.
// Consumer loads are 8 consecutive fully-coalesced dwordx4 per wave per step.
// Producer map for element (n, k):  ts=k>>7, w=n>>5, bfi=(n>>4)&1, ak=(k>>5)&3,
//   l=((k>>3)&3)*16+(n&15), byte=(k&7)*2.
// ---------------------------------------------------------------------------

// C = A(fp32, lda) @ B(Bp layout, K) with fused epilogue.
// OUTT: write bf16 output in Bp layout (opt. scaled by filt[m]); else fp32 C[m][n].
template <bool SCALE, bool OUTT>
__global__ __launch_bounds__(NTHREADS, 1) void gemm_fused(
    const float* __restrict__ A, const bf16* __restrict__ Bp,
    const float* __restrict__ filt, void* __restrict__ outp,
    const int K, const int lda) {
  __shared__ char lds[2][LDS_A_BYTES];
  const int t = threadIdx.x;
  const int w = t >> 6;
  const int l = t & 63;
  const int m0 = blockIdx.x * BM;
  const int NT = K / BK;

  // ---- A staging map: thread -> (row, 8-float chunk); cvt bf16, swizzled ds_write
  const int ar = t >> 4;
  const int acb = t & 15;
  const float* gA = A + (size_t)(m0 + ar) * (size_t)lda + acb * 8;
  const int a_lds_off = (ar * (BK * 2) + acb * 16) ^ ((ar & 7) << 4);

  // ---- A fragment read offsets (XOR-swizzled, [32 rows][256 B] tile)
  int aoff[2][4];
#pragma unroll
  for (int af = 0; af < 2; ++af)
#pragma unroll
    for (int ak = 0; ak < 4; ++ak) {
      const int r = af * 16 + (l & 15);
      const int kb = ak * 64 + (l >> 4) * 16;
      aoff[af][ak] = (r * (BK * 2) + kb) ^ ((r & 7) << 4);
    }

  // ---- B per-wave/lane base in Bp layout
  const char* pBw = (const char*)Bp + w * 8192 + l * 16;

  f32x4 acc[2][2] = {};

  // ================= prologue =================
  f32x4 aS0a = __builtin_nontemporal_load((const f32x4*)gA);
  f32x4 aS0b = __builtin_nontemporal_load((const f32x4*)gA + 1);
  f32x4 aS1a = __builtin_nontemporal_load((const f32x4*)(gA + BK));
  f32x4 aS1b = __builtin_nontemporal_load((const f32x4*)(gA + BK) + 1);
  bf16x8 Bc[2][4], Bn[2][4];
#pragma unroll
  for (int bfi = 0; bfi < 2; ++bfi)
#pragma unroll
    for (int ak = 0; ak < 4; ++ak)
      Bc[bfi][ak] = *(const bf16x8*)(pBw + (bfi * 4 + ak) * 1024);
  {
    bf16x8 pk;
#pragma unroll
    for (int j = 0; j < 4; ++j) {
      pk[j] = (bf16)aS0a[j];
      pk[j + 4] = (bf16)aS0b[j];
    }
    *(bf16x8*)(lds[0] + a_lds_off) = pk;
  }
  asm volatile("s_waitcnt lgkmcnt(0)" ::: "memory");
  SBAR;
  SCHED0;

  // ================= main loop (x2 unrolled, static reg sets) =================
  // BODY(TS): ds_read A-frags from lds[P]; issue B(TS+1)->BNXT (coalesced 1KB
  // dwordx4, register-resident, barrier-independent), A(TS+2)->AL (nontemporal);
  // MFMA(afr x BCUR); cvt AW(=A(TS+1)) -> lds[P^1]; lgkm drain; barrier.
#define BODY(TS, P, BCUR, BNXT, AW0, AW1, AL0, AL1)                           \
  {                                                                           \
    const char* bb = lds[P];                                                  \
    bf16x8 afr[2][4];                                                         \
    _Pragma("unroll") for (int af = 0; af < 2; ++af)                          \
        _Pragma("unroll") for (int ak = 0; ak < 4; ++ak)                      \
            afr[af][ak] = *(const bf16x8*)(bb + aoff[af][ak]);                \
    SCHED0;                                                                   \
    const size_t kb1 = (size_t)((((TS) + 1) < NT ? ((TS) + 1) : 0)) << 16;    \
    _Pragma("unroll") for (int bfi = 0; bfi < 2; ++bfi)                       \
        _Pragma("unroll") for (int ak = 0; ak < 4; ++ak)                      \
            BNXT[bfi][ak] =                                                   \
                *(const bf16x8*)(pBw + kb1 + (bfi * 4 + ak) * 1024);          \
    SCHED0;                                                                   \
    const int ka2 = (((TS) + 2) < NT ? ((TS) + 2) : 0) * BK;                  \
    AL0 = __builtin_nontemporal_load((const f32x4*)(gA + ka2));               \
    AL1 = __builtin_nontemporal_load((const f32x4*)(gA + ka2) + 1);           \
    SCHED0;                                                                   \
    asm volatile("s_waitcnt lgkmcnt(0)" ::: "memory");                        \
    SCHED0;                                                                   \
    __builtin_amdgcn_s_setprio(1);                                            \
    _Pragma("unroll") for (int ak = 0; ak < 4; ++ak)                          \
        _Pragma("unroll") for (int af = 0; af < 2; ++af)                      \
            _Pragma("unroll") for (int bfi = 0; bfi < 2; ++bfi)               \
                acc[af][bfi] = __builtin_amdgcn_mfma_f32_16x16x32_bf16(       \
                    afr[af][ak], BCUR[bfi][ak], acc[af][bfi], 0, 0, 0);       \
    __builtin_amdgcn_s_setprio(0);                                            \
    SCHED0;                                                                   \
    {                                                                         \
      bf16x8 pk;                                                              \
      _Pragma("unroll") for (int j = 0; j < 4; ++j) {                         \
        pk[j] = (bf16)AW0[j];                                                 \
        pk[j + 4] = (bf16)AW1[j];                                             \
      }                                                                       \
      *(bf16x8*)(lds[P ^ 1] + a_lds_off) = pk;                                \
    }                                                                         \
    asm volatile("s_waitcnt lgkmcnt(0)" ::: "memory");                        \
    SBAR;                                                                     \
    SCHED0;                                                                   \
  }

  for (int ts = 0; ts < NT; ts += 2) {
    BODY(ts, 0, Bc, Bn, aS1a, aS1b, aS0a, aS0b);
    BODY(ts + 1, 1, Bn, Bc, aS0a, aS0b, aS1a, aS1b);
  }
#undef BODY

  // ---- epilogue (C/D: col = lane&15, row = (lane>>4)*4 + reg)
#pragma unroll
  for (int af = 0; af < 2; ++af)
#pragma unroll
    for (int bfi = 0; bfi < 2; ++bfi) {
      const int mb = m0 + af * 16 + (l >> 4) * 4;
      const int n = w * 32 + bfi * 16 + (l & 15);
      f32x4 v = acc[af][bfi];
      if (SCALE) {
#pragma unroll
        for (int j = 0; j < 4; ++j) v[j] *= filt[mb + j];
      }
      if (OUTT) {
        // write bf16 in Bp (fragment-permuted) layout for the next GEMM
        bf16x4 pv;
#pragma unroll
        for (int j = 0; j < 4; ++j) pv[j] = (bf16)v[j];
        const int ts = mb >> 7, wq = n >> 5, bq = (n >> 4) & 1, aq = (mb >> 5) & 3;
        const int lq = ((mb >> 3) & 3) * 16 + (n & 15);
        char* dst = (char*)outp +
                    (size_t)(((ts * 64 + wq * 8 + bq * 4 + aq) << 10) + lq * 16 +
                             (mb & 7) * 2);
        *(bf16x4*)dst = pv;
      } else {
        float* po = (float*)outp + (size_t)mb * NOUT + n;
#pragma unroll
        for (int j = 0; j < 4; ++j) po[(size_t)j * NOUT] = v[j];
      }
    }
}

// W [256 k][256 n] fp32 -> Wp bf16 in Bp layout
__global__ void prep_wt(const float* __restrict__ W, bf16* __restrict__ Wp) {
  const int k = blockIdx.x;
  const int n = threadIdx.x;
  const int off = (((k >> 7) * 64 + (n >> 5) * 8 + ((n >> 4) & 1) * 4 +
                    ((k >> 5) & 3)) << 10) +
                  (((k >> 3) & 3) * 16 + (n & 15)) * 16 + (k & 7) * 2;
  *(bf16*)((char*)Wp + off) = (bf16)W[k * 256 + n];
}

extern "C" void kernel_launch(void* const* d_in, const int* in_sizes, int n_in,
                              void* d_out, int out_size, void* d_ws, size_t ws_size,
                              hipStream_t stream) {
  const float* features = (const float*)d_in[0];
  const float* wavelets = (const float*)d_in[1];
  const float* wavelets_inv = (const float*)d_in[2];
  const float* W = (const float*)d_in[3];
  const float* filt = (const float*)d_in[4];
  float* out = (float*)d_out;

  char* ws = (char*)d_ws;
  bf16* Wp = (bf16*)ws;                       // 128 KiB, Bp layout (K=256)
  bf16* Tp = (bf16*)(ws + 131072);            // 4 MiB, Bp layout (K=8192)
  bf16* Fp = (bf16*)(ws + 131072 + 4194304);  // 4 MiB, Bp layout (K=8192)

  prep_wt<<<256, 256, 0, stream>>>(W, Wp);
  gemm_fused<false, true><<<256, NTHREADS, 0, stream>>>(features, Wp, nullptr, Tp, 256, 256);
  gemm_fused<true, true><<<256, NTHREADS, 0, stream>>>(wavelets_inv, Tp, filt, Fp, 8192, 8192);
  gemm_fused<false, false><<<256, NTHREADS, 0, stream>>>(wavelets, Fp, nullptr, out, 8192, 8192);
}